// Round 1
// 188.064 us; speedup vs baseline: 1.0094x; 1.0094x over previous
//
#include <hip/hip_runtime.h>
#include <hip/hip_bf16.h>

#define N_EXPERTS 8
#define T_TOKENS 32768
#define D 512            // D_IN == D_OUT
#define TILE 128
#define BK 64
#define MAX_MTILES 264   // ceil((32768 + 8*127) / 128)
#define SORT_CAP (MAX_MTILES * TILE)   // 33792
#define NT (D / TILE)                  // 4 n-tiles
#define GRID_WG (NT * MAX_MTILES)      // 1056, divisible by 8 (bijective XCD swizzle)

typedef __bf16 bf16x8 __attribute__((ext_vector_type(8)));
typedef float  f32x4  __attribute__((ext_vector_type(4)));
typedef unsigned short u16x8 __attribute__((ext_vector_type(8)));

__device__ __forceinline__ unsigned short f2bf(float f) {
    unsigned int u = __float_as_uint(f);
    u += 0x7FFFu + ((u >> 16) & 1u);   // round-to-nearest-even
    return (unsigned short)(u >> 16);
}

// load 8 contiguous fp32, convert to bf16x8 (kept in 4 VGPRs across the barrier)
__device__ __forceinline__ u16x8 ldcvt8(const float* p) {
    float4 a = *(const float4*)p;
    float4 b = *(const float4*)(p + 4);
    u16x8 o;
    o[0] = f2bf(a.x); o[1] = f2bf(a.y); o[2] = f2bf(a.z); o[3] = f2bf(a.w);
    o[4] = f2bf(b.x); o[5] = f2bf(b.y); o[6] = f2bf(b.z); o[7] = f2bf(b.w);
    return o;
}

__device__ __forceinline__ void gl2lds16(const void* g, void* l) {
    // async global->LDS, 16B/lane; LDS dest = wave-uniform base + lane*16
    __builtin_amdgcn_global_load_lds(
        (const __attribute__((address_space(1))) void*)g,
        (__attribute__((address_space(3))) void*)l, 16, 0, 0);
}

// ---- pass 1: per-expert histogram ----
__global__ void hist_kernel(const int* __restrict__ p, int* __restrict__ counts) {
    __shared__ int h[N_EXPERTS];
    int tid = threadIdx.x;
    if (tid < N_EXPERTS) h[tid] = 0;
    __syncthreads();
    for (int t = blockIdx.x * blockDim.x + tid; t < T_TOKENS; t += gridDim.x * blockDim.x)
        atomicAdd(&h[p[t]], 1);
    __syncthreads();
    if (tid < N_EXPERTS) atomicAdd(&counts[tid], h[tid]);
}

// ---- pass 2: scatter token ids (two-level, low-contention); padded prefix inline ----
__global__ void scatter_kernel(const int* __restrict__ p, const int* __restrict__ counts,
                               int* __restrict__ fill, int* __restrict__ sorted) {
    __shared__ int lcount[N_EXPERTS];
    __shared__ int lbase[N_EXPERTS];
    __shared__ int sps[N_EXPERTS];
    int tid = threadIdx.x;
    if (tid < N_EXPERTS) lcount[tid] = 0;
    __syncthreads();
    int t = blockIdx.x * blockDim.x + tid;
    int e = 0, lrank = 0;
    if (t < T_TOKENS) {
        e = p[t];
        lrank = atomicAdd(&lcount[e], 1);
    }
    __syncthreads();
    if (tid < N_EXPERTS)
        lbase[tid] = (lcount[tid] > 0) ? atomicAdd(&fill[tid], lcount[tid]) : 0;
    if (tid == 0) {   // padded exclusive prefix, computed locally (offsets kernel fused away)
        int acc = 0;
#pragma unroll
        for (int i = 0; i < N_EXPERTS; i++) {
            sps[i] = acc;
            acc += (counts[i] + TILE - 1) & ~(TILE - 1);
        }
    }
    __syncthreads();
    if (t < T_TOKENS)
        sorted[sps[e] + lbase[e] + lrank] = t;
}

// ---- pass 3: convert W fp32 -> bf16 (8 MB read, 4 MB write) ----
__global__ __launch_bounds__(256) void convert_w(
        const float* __restrict__ W, unsigned short* __restrict__ Wb) {
    size_t i = (size_t)(blockIdx.x * 256 + threadIdx.x) * 8;   // 8 floats/thread
    *(u16x8*)&Wb[i] = ldcvt8(W + i);
}

// ---- pass 4: fused grouped GEMM ----
// A: gathered fp32 -> bf16 register staging -> XOR-swizzled ds_write_b128
// B: pre-converted bf16 via global_load_lds (global-side XOR swizzle)
// LDS image both sides: slot (row, c) holds global 16B-block (c ^ (row&7))
__global__ __launch_bounds__(256, 4) void moe_gemm_fused(
        const float* __restrict__ x, const unsigned short* __restrict__ Wb,
        const float* __restrict__ bias, const int* __restrict__ counts,
        const int* __restrict__ sorted, float* __restrict__ out) {
    __shared__ int s_idx[TILE];
    __shared__ unsigned short sA[TILE * BK];   // 16 KB
    __shared__ unsigned short sB[TILE * BK];   // 16 KB

    // XCD-bijective swizzle: the 4 n-tiles of one m-tile land on the SAME XCD
    int lid = blockIdx.x;
    int v = (lid & 7) * (GRID_WG / 8) + (lid >> 3);
    int bm = v >> 2, bn = v & 3;
    int row0 = bm * TILE;

    // expert find + total from counts (padded prefix, unrolled, no arrays)
    int acc_off = 0, e = 0, found = 0;
#pragma unroll
    for (int i = 0; i < N_EXPERTS; i++) {
        int c = (counts[i] + TILE - 1) & ~(TILE - 1);
        if (!found && row0 < acc_off + c) { e = i; found = 1; }
        acc_off += c;
    }
    if (row0 >= acc_off) return;   // beyond padded total

    int tid = threadIdx.x;
    if (tid < TILE) s_idx[tid] = sorted[row0 + tid];
    __syncthreads();

    int wave = tid >> 6, lane = tid & 63;
    int wm = (wave >> 1) * 64, wn = (wave & 1) * 64;
    int lrow = lane & 15, lq = lane >> 4;
    int srow = lane >> 3, scol = lane & 7, swz = scol ^ srow;

    // A gather pointers: 4 rows/thread; pad rows (tok<0) read row 0 (values land
    // only in discarded C rows -- store is token-guarded)
    const float* aptr[4];
#pragma unroll
    for (int t = 0; t < 4; t++) {
        int tok = s_idx[wave * 32 + t * 8 + srow];
        aptr[t] = x + (size_t)(tok < 0 ? 0 : tok) * D + swz * 8;
    }
    const unsigned short* gB = Wb + (size_t)e * D * D
                             + (size_t)(bn * TILE + wave * 32 + srow) * D + swz * 8;
    unsigned short* lB = sB + (wave * 32) * BK;

    // prologue: A tile for kk=0 into registers
    u16x8 pa[4];
#pragma unroll
    for (int t = 0; t < 4; t++) pa[t] = ldcvt8(aptr[t]);

    f32x4 acc[4][4];
#pragma unroll
    for (int i = 0; i < 4; i++)
#pragma unroll
        for (int j = 0; j < 4; j++)
            acc[i][j] = (f32x4){0.f, 0.f, 0.f, 0.f};

    for (int kk = 0; kk < D; kk += BK) {
        __syncthreads();   // prev iter's ds_reads done before overwriting LDS
        // A: swizzled ds_write from registers (regs ready -- loaded before prev barrier)
#pragma unroll
        for (int t = 0; t < 4; t++) {
            int r = wave * 32 + t * 8 + srow;
            *(u16x8*)&sA[r * BK + scol * 8] = pa[t];
        }
        // B: async DMA into LDS
#pragma unroll
        for (int t = 0; t < 4; t++)
            gl2lds16(gB + (size_t)(t * 8) * D + kk, lB + t * 8 * BK);
        // prefetch next A tile into registers -- latency merges with B's DMA
        // into the single vmcnt(0) drain at the barrier below
        if (kk + BK < D) {
#pragma unroll
            for (int t = 0; t < 4; t++) pa[t] = ldcvt8(aptr[t] + kk + BK);
        }
        __syncthreads();   // drain DMA (vmcnt0) + lgkm; all waves see LDS
#pragma unroll
        for (int ks = 0; ks < 2; ks++) {
            bf16x8 af[4], bfr[4];
#pragma unroll
            for (int i = 0; i < 4; i++) {
                int row = wm + 16 * i + lrow;
                int cb = (ks * 4 + lq) ^ (lrow & 7);
                af[i] = *(const bf16x8*)&sA[row * BK + cb * 8];
            }
#pragma unroll
            for (int j = 0; j < 4; j++) {
                int row = wn + 16 * j + lrow;
                int cb = (ks * 4 + lq) ^ (lrow & 7);
                bfr[j] = *(const bf16x8*)&sB[row * BK + cb * 8];
            }
#pragma unroll
            for (int i = 0; i < 4; i++)
#pragma unroll
                for (int j = 0; j < 4; j++)
                    acc[i][j] = __builtin_amdgcn_mfma_f32_16x16x32_bf16(
                        af[i], bfr[j], acc[i][j], 0, 0, 0);
        }
    }

    // epilogue: bias + scatter rows back by token id
    // C/D layout: col = lane&15 (n), row = (lane>>4)*4 + reg (m)
#pragma unroll
    for (int j = 0; j < 4; j++) {
        int ng = bn * TILE + wn + 16 * j + lrow;
        float bv = bias[e * D + ng];
#pragma unroll
        for (int i = 0; i < 4; i++) {
#pragma unroll
            for (int r = 0; r < 4; r++) {
                int mrow = wm + 16 * i + lq * 4 + r;
                int tok = s_idx[mrow];
                if (tok >= 0)
                    out[(size_t)tok * D + ng] = acc[i][j][r] + bv;
            }
        }
    }
}

// ---- pass 4 (fallback, tiny ws): fp32-load GEMM, no Wb needed ----
__global__ __launch_bounds__(256) void moe_gemm_f32(
        const float* __restrict__ x, const float* __restrict__ W,
        const float* __restrict__ bias, const int* __restrict__ counts,
        const int* __restrict__ sorted, float* __restrict__ out) {
    __shared__ int s_idx[TILE];
    __shared__ unsigned short sA[TILE][BK + 8];
    __shared__ unsigned short sB[TILE][BK + 8];

    int bm = blockIdx.x, bn = blockIdx.y;
    int row0 = bm * TILE;
    int acc_off = 0, e = 0, found = 0;
#pragma unroll
    for (int i = 0; i < N_EXPERTS; i++) {
        int c = (counts[i] + TILE - 1) & ~(TILE - 1);
        if (!found && row0 < acc_off + c) { e = i; found = 1; }
        acc_off += c;
    }
    if (row0 >= acc_off) return;

    int tid = threadIdx.x;
    if (tid < TILE) s_idx[tid] = sorted[row0 + tid];
    __syncthreads();

    const float* Wb = W + (size_t)e * D * D + (size_t)(bn * TILE) * D;

    f32x4 acc[4][4];
#pragma unroll
    for (int i = 0; i < 4; i++)
#pragma unroll
        for (int j = 0; j < 4; j++)
            acc[i][j] = (f32x4){0.f, 0.f, 0.f, 0.f};

    int wave = tid >> 6, lane = tid & 63;
    int wm = (wave >> 1) * 64, wn = (wave & 1) * 64;
    int lrow = lane & 15, lq = lane >> 4;

    for (int kk = 0; kk < D; kk += BK) {
#pragma unroll
        for (int i = 0; i < 8; i++) {
            int flat = tid + i * 256;
            int r = flat >> 4, c = (flat & 15) << 2;
            int tok = s_idx[r];
            float4 v = make_float4(0.f, 0.f, 0.f, 0.f);
            if (tok >= 0) v = *(const float4*)(x + (size_t)tok * D + kk + c);
            ushort4 w4;
            w4.x = f2bf(v.x); w4.y = f2bf(v.y); w4.z = f2bf(v.z); w4.w = f2bf(v.w);
            *(ushort4*)&sA[r][c] = w4;
        }
#pragma unroll
        for (int i = 0; i < 8; i++) {
            int flat = tid + i * 256;
            int r = flat >> 4, c = (flat & 15) << 2;
            float4 v = *(const float4*)(Wb + (size_t)r * D + kk + c);
            ushort4 w4;
            w4.x = f2bf(v.x); w4.y = f2bf(v.y); w4.z = f2bf(v.z); w4.w = f2bf(v.w);
            *(ushort4*)&sB[r][c] = w4;
        }
        __syncthreads();
#pragma unroll
        for (int ks = 0; ks < 2; ks++) {
            bf16x8 af[4], bfr[4];
#pragma unroll
            for (int i = 0; i < 4; i++)
                af[i] = *(const bf16x8*)&sA[wm + 16 * i + lrow][ks * 32 + lq * 8];
#pragma unroll
            for (int j = 0; j < 4; j++)
                bfr[j] = *(const bf16x8*)&sB[wn + 16 * j + lrow][ks * 32 + lq * 8];
#pragma unroll
            for (int i = 0; i < 4; i++)
#pragma unroll
                for (int j = 0; j < 4; j++)
                    acc[i][j] = __builtin_amdgcn_mfma_f32_16x16x32_bf16(
                        af[i], bfr[j], acc[i][j], 0, 0, 0);
        }
        __syncthreads();
    }

#pragma unroll
    for (int j = 0; j < 4; j++) {
        int ng = bn * TILE + wn + 16 * j + lrow;
        float bv = bias[e * D + ng];
#pragma unroll
        for (int i = 0; i < 4; i++) {
#pragma unroll
            for (int r = 0; r < 4; r++) {
                int mrow = wm + 16 * i + lq * 4 + r;
                int tok = s_idx[mrow];
                if (tok >= 0)
                    out[(size_t)tok * D + ng] = acc[i][j][r] + bv;
            }
        }
    }
}

extern "C" void kernel_launch(void* const* d_in, const int* in_sizes, int n_in,
                              void* d_out, int out_size, void* d_ws, size_t ws_size,
                              hipStream_t stream) {
    const float* x    = (const float*)d_in[0];
    const int*   part = (const int*)d_in[1];
    const float* W    = (const float*)d_in[2];
    const float* b    = (const float*)d_in[3];
    float* out = (float*)d_out;

    const size_t wb_elems = (size_t)N_EXPERTS * D * D;   // bf16
    const size_t fast_bytes = wb_elems * 2 + SORT_CAP * 4 + 16 * 4;

    if (ws_size >= fast_bytes) {
        unsigned short* Wb = (unsigned short*)d_ws;
        int* sorted = (int*)(Wb + wb_elems);
        int* counts = sorted + SORT_CAP;
        int* fill   = counts + N_EXPERTS;

        hipMemsetAsync(sorted, 0xFF, SORT_CAP * sizeof(int), stream);
        hipMemsetAsync(counts, 0, 2 * N_EXPERTS * sizeof(int), stream);

        hist_kernel<<<64, 256, 0, stream>>>(part, counts);
        scatter_kernel<<<(T_TOKENS + 255) / 256, 256, 0, stream>>>(part, counts, fill, sorted);
        convert_w<<<(int)(wb_elems / 8 / 256), 256, 0, stream>>>(W, Wb);
        moe_gemm_fused<<<GRID_WG, 256, 0, stream>>>(x, Wb, b, counts, sorted, out);
    } else {
        int* sorted = (int*)d_ws;
        int* counts = sorted + SORT_CAP;
        int* fill   = counts + N_EXPERTS;

        hipMemsetAsync(sorted, 0xFF, SORT_CAP * sizeof(int), stream);
        hipMemsetAsync(counts, 0, 2 * N_EXPERTS * sizeof(int), stream);

        hist_kernel<<<64, 256, 0, stream>>>(part, counts);
        scatter_kernel<<<(T_TOKENS + 255) / 256, 256, 0, stream>>>(part, counts, fill, sorted);

        dim3 grid(MAX_MTILES, D / TILE);
        moe_gemm_f32<<<grid, 256, 0, stream>>>(x, W, b, counts, sorted, out);
    }
}

// Round 2
// 167.904 us; speedup vs baseline: 1.1306x; 1.1201x over previous
//
#include <hip/hip_runtime.h>
#include <hip/hip_bf16.h>

#define N_EXPERTS 8
#define T_TOKENS 32768
#define D 512            // D_IN == D_OUT
#define TILE 128
#define BK 64
#define NT 4                       // n-tiles (D / TILE)
#define LT_MAX 256                 // max m-tiles per expert (T_TOKENS / TILE)
#define GEMM_GRID (N_EXPERTS * LT_MAX * NT)   // 8192
#define SCATTER_BLOCKS (T_TOKENS / 256)       // 128
#define CONVW_BLOCKS ((N_EXPERTS * D * D) / (8 * 256))  // 1024

typedef __bf16 bf16x8 __attribute__((ext_vector_type(8)));
typedef float  f32x4  __attribute__((ext_vector_type(4)));
typedef unsigned short u16x8 __attribute__((ext_vector_type(8)));

__device__ __forceinline__ unsigned short f2bf(float f) {
    unsigned int u = __float_as_uint(f);
    u += 0x7FFFu + ((u >> 16) & 1u);   // round-to-nearest-even
    return (unsigned short)(u >> 16);
}

__device__ __forceinline__ u16x8 cvt8(float4 a, float4 b) {
    u16x8 o;
    o[0] = f2bf(a.x); o[1] = f2bf(a.y); o[2] = f2bf(a.z); o[3] = f2bf(a.w);
    o[4] = f2bf(b.x); o[5] = f2bf(b.y); o[6] = f2bf(b.z); o[7] = f2bf(b.w);
    return o;
}

__device__ __forceinline__ void gl2lds16(const void* g, void* l) {
    // async global->LDS, 16B/lane; LDS dest = wave-uniform base + lane*16
    __builtin_amdgcn_global_load_lds(
        (const __attribute__((address_space(1))) void*)g,
        (__attribute__((address_space(3))) void*)l, 16, 0, 0);
}

// ---- prep: scatter token ids into fixed per-expert regions (+1 trick: fill
// starts at -1 from the 0xFF memset) AND convert W fp32->bf16, one kernel ----
__global__ __launch_bounds__(256) void prep_kernel(
        const int* __restrict__ p, int* __restrict__ fill, int* __restrict__ sorted,
        const float* __restrict__ W, unsigned short* __restrict__ Wb) {
    int bid = blockIdx.x;
    int tid = threadIdx.x;
    if (bid < SCATTER_BLOCKS) {
        __shared__ int lcount[N_EXPERTS];
        __shared__ int lbase[N_EXPERTS];
        if (tid < N_EXPERTS) lcount[tid] = 0;
        __syncthreads();
        int t = bid * 256 + tid;            // always < T_TOKENS (128*256 == 32768)
        int e = p[t];
        int lrank = atomicAdd(&lcount[e], 1);
        __syncthreads();
        if (tid < N_EXPERTS)
            lbase[tid] = (lcount[tid] > 0) ? atomicAdd(&fill[tid], lcount[tid]) : 0;
        __syncthreads();
        // fill starts at -1, atomicAdd returns old => first rank is (-1)+1+0 = 0
        sorted[e * T_TOKENS + (lbase[e] + 1 + lrank)] = t;
    } else {
        size_t i = ((size_t)(bid - SCATTER_BLOCKS) * 256 + tid) * 8;
        float4 a = *(const float4*)(W + i);
        float4 b = *(const float4*)(W + i + 4);
        *(u16x8*)&Wb[i] = cvt8(a, b);
    }
}

// ---- fused grouped GEMM, fully pipelined 2-phase ----
// A: gathered fp32 rows -> raw float4 regs (loaded one K-step early) ->
//    cvt bf16 + XOR-swizzled ds_write next step (T14 split: load & convert
//    are in DIFFERENT phases, so HBM/L3 latency hides under the MFMAs).
// B: pre-converted bf16 via global_load_lds into DOUBLE-BUFFERED LDS, issued
//    one K-step early. Issue order per step is B-then-A: vmcnt retires in
//    order, so the cvt's wait on A(k) implies B(k)'s DMA completed -- no
//    explicit vmcnt wait needed anywhere.
// Barriers are raw s_barrier + lgkmcnt(0) only (no compiler vmcnt(0) drain),
// so prefetches stay in flight across both barriers.
__global__ __launch_bounds__(256, 3) void moe_gemm_fused(
        const float* __restrict__ x, const unsigned short* __restrict__ Wb,
        const float* __restrict__ bias, const int* __restrict__ fill,
        const int* __restrict__ sorted, float* __restrict__ out) {
    __shared__ int s_idx[TILE];
    __shared__ unsigned short sA[TILE * BK];        // 16 KB, single-buffered
    __shared__ unsigned short sB[2][TILE * BK];     // 2 x 16 KB, double-buffered

    // decode: e in low 3 bits => all of one expert's blocks on one XCD
    // (its 512 KB Wb slab becomes L2-resident); bn fastest among the rest so
    // the 4 n-tiles sharing an A-tile dispatch adjacently.
    int bid = blockIdx.x;
    int e = bid & 7;
    int cnt = fill[e] + 1;                 // +1 trick (fill started at -1)
    int j = bid >> 3;
    int lt = j >> 2, bn = j & 3;
    int row0 = lt * TILE;
    if (row0 >= cnt) return;

    int tid = threadIdx.x;
    if (tid < TILE) {
        int r = row0 + tid;
        s_idx[tid] = (r < cnt) ? sorted[e * T_TOKENS + r] : -1;
    }
    __syncthreads();

    int wave = tid >> 6, lane = tid & 63;
    int wm = (wave >> 1) * 64, wn = (wave & 1) * 64;
    int lrow = lane & 15, lq = lane >> 4;
    int srow = lane >> 3, scol = lane & 7, swz = scol ^ srow;

    // A gather pointers: 4 rows/thread; pad rows (tok<0) read row 0 (their
    // products land only in discarded C rows -- store is token-guarded)
    const float* aptr[4];
#pragma unroll
    for (int t = 0; t < 4; t++) {
        int tok = s_idx[wave * 32 + t * 8 + srow];
        aptr[t] = x + (size_t)(tok < 0 ? 0 : tok) * D + swz * 8;
    }
    const unsigned short* gB = Wb + (size_t)e * D * D
                             + (size_t)(bn * TILE + wave * 32 + srow) * D + swz * 8;

    // prologue: B(0) DMA first, then A(0) loads (order matters: in-order vmcnt)
#pragma unroll
    for (int t = 0; t < 4; t++)
        gl2lds16(gB + (size_t)(t * 8) * D, &sB[0][(wave * 32 + t * 8) * BK]);
    __builtin_amdgcn_sched_barrier(0);
    float4 pa[8];
#pragma unroll
    for (int t = 0; t < 4; t++) {
        pa[2 * t]     = *(const float4*)(aptr[t]);
        pa[2 * t + 1] = *(const float4*)(aptr[t] + 4);
    }

    f32x4 acc[4][4];
#pragma unroll
    for (int i = 0; i < 4; i++)
#pragma unroll
        for (int j2 = 0; j2 < 4; j2++)
            acc[i][j2] = (f32x4){0.f, 0.f, 0.f, 0.f};

#pragma unroll
    for (int step = 0; step < 8; step++) {
        const int kk = step * BK;
        // ---- top barrier: previous step's ds_reads all retired (their data
        // was consumed by MFMA issue), so LDS may be overwritten after this.
        asm volatile("s_waitcnt lgkmcnt(0)" ::: "memory");
        __builtin_amdgcn_s_barrier();
        __builtin_amdgcn_sched_barrier(0);
        // ---- convert + swizzled write A(kk). The implicit vmcnt wait here is
        // for loads issued a full step ago (and, being older, B(kk)'s DMA).
#pragma unroll
        for (int t = 0; t < 4; t++) {
            u16x8 av = cvt8(pa[2 * t], pa[2 * t + 1]);
            *(u16x8*)&sA[(wave * 32 + t * 8 + srow) * BK + scol * 8] = av;
        }
        __builtin_amdgcn_sched_barrier(0);
        if (step < 7) {
            // issue B(kk+1) DMA into the other buffer...
#pragma unroll
            for (int t = 0; t < 4; t++)
                gl2lds16(gB + (size_t)(t * 8) * D + kk + BK,
                         &sB[(step + 1) & 1][(wave * 32 + t * 8) * BK]);
            __builtin_amdgcn_sched_barrier(0);
            // ...then A(kk+1) raw loads (AFTER the DMA: in-order vmcnt makes
            // next step's A-wait imply B's completion)
#pragma unroll
            for (int t = 0; t < 4; t++) {
                pa[2 * t]     = *(const float4*)(aptr[t] + kk + BK);
                pa[2 * t + 1] = *(const float4*)(aptr[t] + kk + BK + 4);
            }
            __builtin_amdgcn_sched_barrier(0);
        }
        // ---- bottom barrier: own ds_writes visible (lgkm only; vmem prefetch
        // stays in flight across the barrier)
        asm volatile("s_waitcnt lgkmcnt(0)" ::: "memory");
        __builtin_amdgcn_s_barrier();
        __builtin_amdgcn_sched_barrier(0);
        const unsigned short* sBc = sB[step & 1];
#pragma unroll
        for (int ks = 0; ks < 2; ks++) {
            bf16x8 af[4], bfr[4];
#pragma unroll
            for (int i = 0; i < 4; i++) {
                int row = wm + 16 * i + lrow;
                int cb = (ks * 4 + lq) ^ (lrow & 7);
                af[i] = *(const bf16x8*)&sA[row * BK + cb * 8];
            }
#pragma unroll
            for (int j2 = 0; j2 < 4; j2++) {
                int row = wn + 16 * j2 + lrow;
                int cb = (ks * 4 + lq) ^ (lrow & 7);
                bfr[j2] = *(const bf16x8*)&sBc[row * BK + cb * 8];
            }
#pragma unroll
            for (int i = 0; i < 4; i++)
#pragma unroll
                for (int j2 = 0; j2 < 4; j2++)
                    acc[i][j2] = __builtin_amdgcn_mfma_f32_16x16x32_bf16(
                        af[i], bfr[j2], acc[i][j2], 0, 0, 0);
        }
    }

    // epilogue: bias + scatter rows back by token id
    // C/D layout: col = lane&15 (n), row = (lane>>4)*4 + reg (m)
#pragma unroll
    for (int j2 = 0; j2 < 4; j2++) {
        int ng = bn * TILE + wn + 16 * j2 + lrow;
        float bv = bias[e * D + ng];
#pragma unroll
        for (int i = 0; i < 4; i++) {
#pragma unroll
            for (int r = 0; r < 4; r++) {
                int mrow = wm + 16 * i + lq * 4 + r;
                int tok = s_idx[mrow];
                if (tok >= 0)
                    out[(size_t)tok * D + ng] = acc[i][j2][r] + bv;
            }
        }
    }
}

// ---- fallback (tiny ws): fp32-load GEMM, fixed-region decode ----
__global__ __launch_bounds__(256) void moe_gemm_f32(
        const float* __restrict__ x, const float* __restrict__ W,
        const float* __restrict__ bias, const int* __restrict__ fill,
        const int* __restrict__ sorted, float* __restrict__ out) {
    __shared__ int s_idx[TILE];
    __shared__ unsigned short sA[TILE][BK + 8];
    __shared__ unsigned short sB[TILE][BK + 8];

    int bid = blockIdx.x;
    int e = bid & 7;
    int cnt = fill[e] + 1;
    int j = bid >> 3;
    int lt = j >> 2, bn = j & 3;
    int row0 = lt * TILE;
    if (row0 >= cnt) return;

    int tid = threadIdx.x;
    if (tid < TILE) {
        int r = row0 + tid;
        s_idx[tid] = (r < cnt) ? sorted[e * T_TOKENS + r] : -1;
    }
    __syncthreads();

    const float* Wb = W + (size_t)e * D * D + (size_t)(bn * TILE) * D;

    f32x4 acc[4][4];
#pragma unroll
    for (int i = 0; i < 4; i++)
#pragma unroll
        for (int j2 = 0; j2 < 4; j2++)
            acc[i][j2] = (f32x4){0.f, 0.f, 0.f, 0.f};

    int wave = tid >> 6, lane = tid & 63;
    int wm = (wave >> 1) * 64, wn = (wave & 1) * 64;
    int lrow = lane & 15, lq = lane >> 4;

    for (int kk = 0; kk < D; kk += BK) {
#pragma unroll
        for (int i = 0; i < 8; i++) {
            int flat = tid + i * 256;
            int r = flat >> 4, c = (flat & 15) << 2;
            int tok = s_idx[r];
            float4 v = make_float4(0.f, 0.f, 0.f, 0.f);
            if (tok >= 0) v = *(const float4*)(x + (size_t)tok * D + kk + c);
            ushort4 w4;
            w4.x = f2bf(v.x); w4.y = f2bf(v.y); w4.z = f2bf(v.z); w4.w = f2bf(v.w);
            *(ushort4*)&sA[r][c] = w4;
        }
#pragma unroll
        for (int i = 0; i < 8; i++) {
            int flat = tid + i * 256;
            int r = flat >> 4, c = (flat & 15) << 2;
            float4 v = *(const float4*)(Wb + (size_t)r * D + kk + c);
            ushort4 w4;
            w4.x = f2bf(v.x); w4.y = f2bf(v.y); w4.z = f2bf(v.z); w4.w = f2bf(v.w);
            *(ushort4*)&sB[r][c] = w4;
        }
        __syncthreads();
#pragma unroll
        for (int ks = 0; ks < 2; ks++) {
            bf16x8 af[4], bfr[4];
#pragma unroll
            for (int i = 0; i < 4; i++)
                af[i] = *(const bf16x8*)&sA[wm + 16 * i + lrow][ks * 32 + lq * 8];
#pragma unroll
            for (int j2 = 0; j2 < 4; j2++)
                bfr[j2] = *(const bf16x8*)&sB[wn + 16 * j2 + lrow][ks * 32 + lq * 8];
#pragma unroll
            for (int i = 0; i < 4; i++)
#pragma unroll
                for (int j2 = 0; j2 < 4; j2++)
                    acc[i][j2] = __builtin_amdgcn_mfma_f32_16x16x32_bf16(
                        af[i], bfr[j2], acc[i][j2], 0, 0, 0);
        }
        __syncthreads();
    }

#pragma unroll
    for (int j2 = 0; j2 < 4; j2++) {
        int ng = bn * TILE + wn + 16 * j2 + lrow;
        float bv = bias[e * D + ng];
#pragma unroll
        for (int i = 0; i < 4; i++) {
#pragma unroll
            for (int r = 0; r < 4; r++) {
                int mrow = wm + 16 * i + lq * 4 + r;
                int tok = s_idx[mrow];
                if (tok >= 0)
                    out[(size_t)tok * D + ng] = acc[i][j2][r] + bv;
            }
        }
    }
}

extern "C" void kernel_launch(void* const* d_in, const int* in_sizes, int n_in,
                              void* d_out, int out_size, void* d_ws, size_t ws_size,
                              hipStream_t stream) {
    const float* x    = (const float*)d_in[0];
    const int*   part = (const int*)d_in[1];
    const float* W    = (const float*)d_in[2];
    const float* b    = (const float*)d_in[3];
    float* out = (float*)d_out;

    const size_t wb_elems     = (size_t)N_EXPERTS * D * D;        // bf16
    const size_t sorted_elems = (size_t)N_EXPERTS * T_TOKENS;     // int
    const size_t fast_bytes   = wb_elems * 2 + (sorted_elems + 8) * 4;
    const size_t slow_bytes   = (sorted_elems + 8) * 4;

    if (ws_size >= fast_bytes) {
        unsigned short* Wb = (unsigned short*)d_ws;
        int* sorted = (int*)(Wb + wb_elems);
        int* fill   = sorted + sorted_elems;

        hipMemsetAsync(fill, 0xFF, N_EXPERTS * sizeof(int), stream);   // fill = -1
        prep_kernel<<<SCATTER_BLOCKS + CONVW_BLOCKS, 256, 0, stream>>>(
            part, fill, sorted, W, Wb);
        moe_gemm_fused<<<GEMM_GRID, 256, 0, stream>>>(x, Wb, b, fill, sorted, out);
    } else if (ws_size >= slow_bytes) {
        int* sorted = (int*)d_ws;
        int* fill   = sorted + sorted_elems;

        hipMemsetAsync(fill, 0xFF, N_EXPERTS * sizeof(int), stream);
        prep_kernel<<<SCATTER_BLOCKS, 256, 0, stream>>>(
            part, fill, sorted, W, (unsigned short*)nullptr);
        moe_gemm_f32<<<GEMM_GRID, 256, 0, stream>>>(x, W, b, fill, sorted, out);
    }
}

// Round 3
// 153.614 us; speedup vs baseline: 1.2358x; 1.0930x over previous
//
#include <hip/hip_runtime.h>
#include <hip/hip_bf16.h>

#define N_EXPERTS 8
#define T_TOKENS 32768
#define D 512            // D_IN == D_OUT
#define TILE 128
#define BK 64
#define NT 4                       // n-tiles (D / TILE)
#define LT_MAX 256                 // max m-tiles per expert (T_TOKENS / TILE)
#define GEMM_GRID (N_EXPERTS * LT_MAX * NT)   // 8192
#define SCATTER_BLOCKS (T_TOKENS / 256)                  // 128
#define CONVW_BLOCKS ((N_EXPERTS * D * D) / (8 * 256))   // 1024
#define CONVX_BLOCKS ((T_TOKENS * D) / (8 * 256))        // 8192

typedef __bf16 bf16x8 __attribute__((ext_vector_type(8)));
typedef float  f32x4  __attribute__((ext_vector_type(4)));
typedef unsigned short u16x8 __attribute__((ext_vector_type(8)));

__device__ __forceinline__ unsigned short f2bf(float f) {
    unsigned int u = __float_as_uint(f);
    u += 0x7FFFu + ((u >> 16) & 1u);   // round-to-nearest-even
    return (unsigned short)(u >> 16);
}

__device__ __forceinline__ u16x8 cvt8(float4 a, float4 b) {
    u16x8 o;
    o[0] = f2bf(a.x); o[1] = f2bf(a.y); o[2] = f2bf(a.z); o[3] = f2bf(a.w);
    o[4] = f2bf(b.x); o[5] = f2bf(b.y); o[6] = f2bf(b.z); o[7] = f2bf(b.w);
    return o;
}

__device__ __forceinline__ void gl2lds16(const void* g, void* l) {
    // async global->LDS, 16B/lane; LDS dest = wave-uniform base + lane*16,
    // GLOBAL source is per-lane (gather-capable)
    __builtin_amdgcn_global_load_lds(
        (const __attribute__((address_space(1))) void*)g,
        (__attribute__((address_space(3))) void*)l, 16, 0, 0);
}

// ---- prep: scatter token ids into fixed per-expert regions, convert W and x
// to bf16, all in one kernel (independent block ranges) ----
__global__ __launch_bounds__(256) void prep_kernel(
        const int* __restrict__ p, int* __restrict__ fill, int* __restrict__ sorted,
        const float* __restrict__ W, unsigned short* __restrict__ Wb,
        const float* __restrict__ x, unsigned short* __restrict__ xb) {
    int bid = blockIdx.x;
    int tid = threadIdx.x;
    if (bid < SCATTER_BLOCKS) {
        __shared__ int lcount[N_EXPERTS];
        __shared__ int lbase[N_EXPERTS];
        if (tid < N_EXPERTS) lcount[tid] = 0;
        __syncthreads();
        int t = bid * 256 + tid;            // always < T_TOKENS (128*256 == 32768)
        int e = p[t];
        int lrank = atomicAdd(&lcount[e], 1);
        __syncthreads();
        if (tid < N_EXPERTS)
            lbase[tid] = (lcount[tid] > 0) ? atomicAdd(&fill[tid], lcount[tid]) : 0;
        __syncthreads();
        // fill starts at -1 (0xFF memset), atomicAdd returns old => first rank 0
        sorted[e * T_TOKENS + (lbase[e] + 1 + lrank)] = t;
    } else if (bid < SCATTER_BLOCKS + CONVW_BLOCKS) {
        size_t i = ((size_t)(bid - SCATTER_BLOCKS) * 256 + tid) * 8;
        float4 a = *(const float4*)(W + i);
        float4 b = *(const float4*)(W + i + 4);
        *(u16x8*)&Wb[i] = cvt8(a, b);
    } else {
        size_t i = ((size_t)(bid - SCATTER_BLOCKS - CONVW_BLOCKS) * 256 + tid) * 8;
        float4 a = *(const float4*)(x + i);
        float4 b = *(const float4*)(x + i + 4);
        *(u16x8*)&xb[i] = cvt8(a, b);
    }
}

// ---- fused grouped GEMM: all-DMA staging + counted vmcnt (T4) + setprio (T5)
// A: bf16 xb rows gathered by token id straight into LDS via global_load_lds
//    (per-lane global address = gather; LDS dest linear = lane*16).
// B: bf16 Wb via global_load_lds. Both double-buffered; XOR swizzle applied on
//    the GLOBAL source 16B-block index, fragment ds_read_b128 hits all banks.
// Per step: issue next-step's 8 DMAs, then s_waitcnt vmcnt(8) -- the next
// stage stays in flight across BOTH barriers; queue only drains at last step.
__global__ __launch_bounds__(256, 2) void moe_gemm_dma(
        const unsigned short* __restrict__ xb, const unsigned short* __restrict__ Wb,
        const float* __restrict__ bias, const int* __restrict__ fill,
        const int* __restrict__ sorted, float* __restrict__ out) {
    __shared__ int s_idx[TILE];
    __shared__ unsigned short buf[2][2][TILE * BK];   // [kbuf][A=0/B=1], 64 KB

    // decode: e in low 3 bits (expert <-> XCD affinity: Wb slab L2-resident);
    // bn fastest so the 4 n-tiles sharing an A-tile dispatch adjacently
    int bid = blockIdx.x;
    int e = bid & 7;
    int cnt = fill[e] + 1;                 // +1 trick (fill started at -1)
    int j = bid >> 3;
    int lt = j >> 2, bn = j & 3;
    int row0 = lt * TILE;
    if (row0 >= cnt) return;

    int tid = threadIdx.x;
    if (tid < TILE) {
        int r = row0 + tid;
        s_idx[tid] = (r < cnt) ? sorted[e * T_TOKENS + r] : -1;
    }
    __syncthreads();   // also drains vmcnt -> DMA counting below starts at 0

    int wave = tid >> 6, lane = tid & 63;
    int wm = (wave >> 1) * 64, wn = (wave & 1) * 64;
    int lrow = lane & 15, lq = lane >> 4;
    int srow = lane >> 3, scol = lane & 7, swz = scol ^ srow;

    // per-lane DMA source pointers (4 gathered A rows + B rows per wave slice);
    // pad rows (tok<0) read xb row 0 -- products land in discarded C rows
    const unsigned short* gA[4];
#pragma unroll
    for (int t = 0; t < 4; t++) {
        int tok = s_idx[wave * 32 + t * 8 + srow];
        gA[t] = xb + (size_t)(tok < 0 ? 0 : tok) * D + swz * 8;
    }
    const unsigned short* gB = Wb + (size_t)e * D * D
                             + (size_t)(bn * TILE + wave * 32 + srow) * D + swz * 8;

#define STAGE(K, KB) do {                                                     \
    _Pragma("unroll") for (int t = 0; t < 4; t++)                             \
        gl2lds16(gA[t] + (K) * BK, &buf[KB][0][(wave * 32 + t * 8) * BK]);    \
    _Pragma("unroll") for (int t = 0; t < 4; t++)                             \
        gl2lds16(gB + (size_t)(t * 8) * D + (K) * BK,                         \
                 &buf[KB][1][(wave * 32 + t * 8) * BK]);                      \
} while (0)

    f32x4 acc[4][4];
#pragma unroll
    for (int i = 0; i < 4; i++)
#pragma unroll
        for (int j2 = 0; j2 < 4; j2++)
            acc[i][j2] = (f32x4){0.f, 0.f, 0.f, 0.f};

    STAGE(0, 0);   // prologue: stage(0) in flight (8 DMAs)

#pragma unroll
    for (int step = 0; step < 8; step++) {
        // top barrier: prev step's ds_reads retired -> buf[(step+1)&1] is free
        asm volatile("s_waitcnt lgkmcnt(0)" ::: "memory");
        __builtin_amdgcn_s_barrier();
        __builtin_amdgcn_sched_barrier(0);
        if (step < 7) {
            STAGE(step + 1, (step + 1) & 1);   // issue next stage (8 DMAs)...
            __builtin_amdgcn_sched_barrier(0);
            // ...then wait ONLY for stage(step): 8 younger ops stay in flight
            asm volatile("s_waitcnt vmcnt(8)" ::: "memory");
        } else {
            asm volatile("s_waitcnt vmcnt(0)" ::: "memory");
        }
        __builtin_amdgcn_s_barrier();          // all waves' stage(step) visible
        __builtin_amdgcn_sched_barrier(0);
        const unsigned short* sA = buf[step & 1][0];
        const unsigned short* sB = buf[step & 1][1];
        __builtin_amdgcn_s_setprio(1);
#pragma unroll
        for (int ks = 0; ks < 2; ks++) {
            bf16x8 af[4], bfr[4];
#pragma unroll
            for (int i = 0; i < 4; i++) {
                int row = wm + 16 * i + lrow;
                int cb = (ks * 4 + lq) ^ (lrow & 7);
                af[i] = *(const bf16x8*)&sA[row * BK + cb * 8];
            }
#pragma unroll
            for (int j2 = 0; j2 < 4; j2++) {
                int row = wn + 16 * j2 + lrow;
                int cb = (ks * 4 + lq) ^ (lrow & 7);
                bfr[j2] = *(const bf16x8*)&sB[row * BK + cb * 8];
            }
#pragma unroll
            for (int i = 0; i < 4; i++)
#pragma unroll
                for (int j2 = 0; j2 < 4; j2++)
                    acc[i][j2] = __builtin_amdgcn_mfma_f32_16x16x32_bf16(
                        af[i], bfr[j2], acc[i][j2], 0, 0, 0);
        }
        __builtin_amdgcn_s_setprio(0);
    }
#undef STAGE

    // ---- coalesced epilogue: fold bias, stage C tile through LDS, write
    // full 512B row-segments (32 lanes x 16B) instead of scattered 64B chunks
#pragma unroll
    for (int j2 = 0; j2 < 4; j2++) {
        float bv = bias[e * D + bn * TILE + wn + 16 * j2 + lrow];
#pragma unroll
        for (int i = 0; i < 4; i++)
#pragma unroll
            for (int r = 0; r < 4; r++)
                acc[i][j2][r] += bv;
    }

    float* ct = (float*)&buf[0][0][0];   // 32 KB: 64 rows x 128 cols f32
#pragma unroll
    for (int p = 0; p < 2; p++) {
        // all MFMA ds_reads done (p=0) / pass-0 ct reads done (p=1)
        asm volatile("s_waitcnt lgkmcnt(0)" ::: "memory");
        __builtin_amdgcn_s_barrier();
        if ((wave >> 1) == p) {          // the 2 waves owning rows [64p,64p+64)
#pragma unroll
            for (int j2 = 0; j2 < 4; j2++)
#pragma unroll
                for (int i = 0; i < 4; i++)
#pragma unroll
                    for (int r = 0; r < 4; r++)
                        ct[(16 * i + lq * 4 + r) * TILE + wn + 16 * j2 + lrow]
                            = acc[i][j2][r];
        }
        asm volatile("s_waitcnt lgkmcnt(0)" ::: "memory");
        __builtin_amdgcn_s_barrier();
#pragma unroll
        for (int k = 0; k < 8; k++) {
            int u = tid + 256 * k;
            int row = u >> 5, ch = u & 31;
            int tok = s_idx[p * 64 + row];
            f32x4 v = *(const f32x4*)&ct[row * TILE + ch * 4];
            if (tok >= 0)
                *(f32x4*)&out[(size_t)tok * D + bn * TILE + ch * 4] = v;
        }
    }
}

// ---- fallback (tiny ws): fp32-load GEMM, fixed-region decode ----
__global__ __launch_bounds__(256) void moe_gemm_f32(
        const float* __restrict__ x, const float* __restrict__ W,
        const float* __restrict__ bias, const int* __restrict__ fill,
        const int* __restrict__ sorted, float* __restrict__ out) {
    __shared__ int s_idx[TILE];
    __shared__ unsigned short sA[TILE][BK + 8];
    __shared__ unsigned short sB[TILE][BK + 8];

    int bid = blockIdx.x;
    int e = bid & 7;
    int cnt = fill[e] + 1;
    int j = bid >> 3;
    int lt = j >> 2, bn = j & 3;
    int row0 = lt * TILE;
    if (row0 >= cnt) return;

    int tid = threadIdx.x;
    if (tid < TILE) {
        int r = row0 + tid;
        s_idx[tid] = (r < cnt) ? sorted[e * T_TOKENS + r] : -1;
    }
    __syncthreads();

    const float* Wbp = W + (size_t)e * D * D + (size_t)(bn * TILE) * D;

    f32x4 acc[4][4];
#pragma unroll
    for (int i = 0; i < 4; i++)
#pragma unroll
        for (int j2 = 0; j2 < 4; j2++)
            acc[i][j2] = (f32x4){0.f, 0.f, 0.f, 0.f};

    int wave = tid >> 6, lane = tid & 63;
    int wm = (wave >> 1) * 64, wn = (wave & 1) * 64;
    int lrow = lane & 15, lq = lane >> 4;

    for (int kk = 0; kk < D; kk += BK) {
#pragma unroll
        for (int i = 0; i < 8; i++) {
            int flat = tid + i * 256;
            int r = flat >> 4, c = (flat & 15) << 2;
            int tok = s_idx[r];
            float4 v = make_float4(0.f, 0.f, 0.f, 0.f);
            if (tok >= 0) v = *(const float4*)(x + (size_t)tok * D + kk + c);
            ushort4 w4;
            w4.x = f2bf(v.x); w4.y = f2bf(v.y); w4.z = f2bf(v.z); w4.w = f2bf(v.w);
            *(ushort4*)&sA[r][c] = w4;
        }
#pragma unroll
        for (int i = 0; i < 8; i++) {
            int flat = tid + i * 256;
            int r = flat >> 4, c = (flat & 15) << 2;
            float4 v = *(const float4*)(Wbp + (size_t)r * D + kk + c);
            ushort4 w4;
            w4.x = f2bf(v.x); w4.y = f2bf(v.y); w4.z = f2bf(v.z); w4.w = f2bf(v.w);
            *(ushort4*)&sB[r][c] = w4;
        }
        __syncthreads();
#pragma unroll
        for (int ks = 0; ks < 2; ks++) {
            bf16x8 af[4], bfr[4];
#pragma unroll
            for (int i = 0; i < 4; i++)
                af[i] = *(const bf16x8*)&sA[wm + 16 * i + lrow][ks * 32 + lq * 8];
#pragma unroll
            for (int j2 = 0; j2 < 4; j2++)
                bfr[j2] = *(const bf16x8*)&sB[wn + 16 * j2 + lrow][ks * 32 + lq * 8];
#pragma unroll
            for (int i = 0; i < 4; i++)
#pragma unroll
                for (int j2 = 0; j2 < 4; j2++)
                    acc[i][j2] = __builtin_amdgcn_mfma_f32_16x16x32_bf16(
                        af[i], bfr[j2], acc[i][j2], 0, 0, 0);
        }
        __syncthreads();
    }

#pragma unroll
    for (int j2 = 0; j2 < 4; j2++) {
        int ng = bn * TILE + wn + 16 * j2 + lrow;
        float bv = bias[e * D + ng];
#pragma unroll
        for (int i = 0; i < 4; i++) {
#pragma unroll
            for (int r = 0; r < 4; r++) {
                int mrow = wm + 16 * i + lq * 4 + r;
                int tok = s_idx[mrow];
                if (tok >= 0)
                    out[(size_t)tok * D + ng] = acc[i][j2][r] + bv;
            }
        }
    }
}

extern "C" void kernel_launch(void* const* d_in, const int* in_sizes, int n_in,
                              void* d_out, int out_size, void* d_ws, size_t ws_size,
                              hipStream_t stream) {
    const float* x    = (const float*)d_in[0];
    const int*   part = (const int*)d_in[1];
    const float* W    = (const float*)d_in[2];
    const float* b    = (const float*)d_in[3];
    float* out = (float*)d_out;

    const size_t xb_elems     = (size_t)T_TOKENS * D;             // bf16
    const size_t wb_elems     = (size_t)N_EXPERTS * D * D;        // bf16
    const size_t sorted_elems = (size_t)N_EXPERTS * T_TOKENS;     // int
    const size_t fast_bytes   = (xb_elems + wb_elems) * 2 + (sorted_elems + 8) * 4;
    const size_t slow_bytes   = (sorted_elems + 8) * 4;

    if (ws_size >= fast_bytes) {
        unsigned short* xb = (unsigned short*)d_ws;
        unsigned short* Wb = xb + xb_elems;
        int* sorted = (int*)(Wb + wb_elems);
        int* fill   = sorted + sorted_elems;

        hipMemsetAsync(fill, 0xFF, N_EXPERTS * sizeof(int), stream);   // fill = -1
        prep_kernel<<<SCATTER_BLOCKS + CONVW_BLOCKS + CONVX_BLOCKS, 256, 0, stream>>>(
            part, fill, sorted, W, Wb, x, xb);
        moe_gemm_dma<<<GEMM_GRID, 256, 0, stream>>>(xb, Wb, b, fill, sorted, out);
    } else if (ws_size >= slow_bytes) {
        int* sorted = (int*)d_ws;
        int* fill   = sorted + sorted_elems;

        hipMemsetAsync(fill, 0xFF, N_EXPERTS * sizeof(int), stream);
        prep_kernel<<<SCATTER_BLOCKS, 256, 0, stream>>>(
            part, fill, sorted, W, (unsigned short*)nullptr,
            x, (unsigned short*)nullptr);
        moe_gemm_f32<<<GEMM_GRID, 256, 0, stream>>>(x, W, b, fill, sorted, out);
    }
}

// Round 4
// 151.639 us; speedup vs baseline: 1.2519x; 1.0130x over previous
//
#include <hip/hip_runtime.h>
#include <hip/hip_bf16.h>

#define N_EXPERTS 8
#define T_TOKENS 32768
#define D 512            // D_IN == D_OUT
#define TILE 128
#define BKD 32                     // main-kernel K-step (33 KB LDS -> 4 blocks/CU)
#define BK 64                      // fallback-kernel K-step
#define NT 4                       // n-tiles (D / TILE)
#define LT_MAX 256                 // max m-tiles per expert (T_TOKENS / TILE)
#define GEMM_GRID (N_EXPERTS * LT_MAX * NT)   // 8192
#define SCATTER_BLOCKS (T_TOKENS / 256)                  // 128
#define CONVW_BLOCKS ((N_EXPERTS * D * D) / (8 * 256))   // 1024
#define CONVX_BLOCKS ((T_TOKENS * D) / (8 * 256))        // 8192

typedef __bf16 bf16x8 __attribute__((ext_vector_type(8)));
typedef float  f32x4  __attribute__((ext_vector_type(4)));
typedef unsigned short u16x8 __attribute__((ext_vector_type(8)));

__device__ __forceinline__ unsigned short f2bf(float f) {
    unsigned int u = __float_as_uint(f);
    u += 0x7FFFu + ((u >> 16) & 1u);   // round-to-nearest-even
    return (unsigned short)(u >> 16);
}

__device__ __forceinline__ u16x8 cvt8(float4 a, float4 b) {
    u16x8 o;
    o[0] = f2bf(a.x); o[1] = f2bf(a.y); o[2] = f2bf(a.z); o[3] = f2bf(a.w);
    o[4] = f2bf(b.x); o[5] = f2bf(b.y); o[6] = f2bf(b.z); o[7] = f2bf(b.w);
    return o;
}

__device__ __forceinline__ void gl2lds16(const void* g, void* l) {
    // async global->LDS, 16B/lane; LDS dest = wave-uniform base + lane*16,
    // GLOBAL source is per-lane (gather-capable)
    __builtin_amdgcn_global_load_lds(
        (const __attribute__((address_space(1))) void*)g,
        (__attribute__((address_space(3))) void*)l, 16, 0, 0);
}

// ---- prep: scatter token ids into fixed per-expert regions, convert W and x
// to bf16, all in one kernel (independent block ranges) ----
__global__ __launch_bounds__(256) void prep_kernel(
        const int* __restrict__ p, int* __restrict__ fill, int* __restrict__ sorted,
        const float* __restrict__ W, unsigned short* __restrict__ Wb,
        const float* __restrict__ x, unsigned short* __restrict__ xb) {
    int bid = blockIdx.x;
    int tid = threadIdx.x;
    if (bid < SCATTER_BLOCKS) {
        __shared__ int lcount[N_EXPERTS];
        __shared__ int lbase[N_EXPERTS];
        if (tid < N_EXPERTS) lcount[tid] = 0;
        __syncthreads();
        int t = bid * 256 + tid;            // always < T_TOKENS (128*256 == 32768)
        int e = p[t];
        int lrank = atomicAdd(&lcount[e], 1);
        __syncthreads();
        if (tid < N_EXPERTS)
            lbase[tid] = (lcount[tid] > 0) ? atomicAdd(&fill[tid], lcount[tid]) : 0;
        __syncthreads();
        // fill starts at -1 (0xFF memset), atomicAdd returns old => first rank 0
        sorted[e * T_TOKENS + (lbase[e] + 1 + lrank)] = t;
    } else if (bid < SCATTER_BLOCKS + CONVW_BLOCKS) {
        size_t i = ((size_t)(bid - SCATTER_BLOCKS) * 256 + tid) * 8;
        float4 a = *(const float4*)(W + i);
        float4 b = *(const float4*)(W + i + 4);
        *(u16x8*)&Wb[i] = cvt8(a, b);
    } else {
        size_t i = ((size_t)(bid - SCATTER_BLOCKS - CONVW_BLOCKS) * 256 + tid) * 8;
        float4 a = *(const float4*)(x + i);
        float4 b = *(const float4*)(x + i + 4);
        *(u16x8*)&xb[i] = cvt8(a, b);
    }
}

// ---- fused grouped GEMM: all-DMA staging, counted vmcnt (T4), setprio (T5),
// BK=32 so LDS = 33 KB -> 4 blocks/CU = 16 waves/CU (latency hiding).
// A: bf16 xb rows gathered by token id via global_load_lds per-lane source.
// B: bf16 Wb via global_load_lds. Both double-buffered.
// Swizzle (64B rows, 4x16B blocks): LDS slot (r,c) holds global block
// c ^ ((r>>1)&3); with the row-parity bank bit this spreads a wave's 64
// ds_read_b128 lanes uniformly over all 32 banks (8 accesses/bank = wave64
// minimum). Staging pre-swizzles the GLOBAL source block index.
__global__ __launch_bounds__(256, 4) void moe_gemm_dma(
        const unsigned short* __restrict__ xb, const unsigned short* __restrict__ Wb,
        const float* __restrict__ bias, const int* __restrict__ fill,
        const int* __restrict__ sorted, float* __restrict__ out) {
    __shared__ int s_idx[TILE];
    __shared__ unsigned short buf[2][2][TILE * BKD];   // [kbuf][A=0/B=1], 32 KB

    // decode: e in low 3 bits (expert <-> XCD affinity: Wb slab L2-resident);
    // bn fastest so the 4 n-tiles sharing an A-tile dispatch adjacently
    int bid = blockIdx.x;
    int e = bid & 7;
    int cnt = fill[e] + 1;                 // +1 trick (fill started at -1)
    int j = bid >> 3;
    int lt = j >> 2, bn = j & 3;
    int row0 = lt * TILE;
    if (row0 >= cnt) return;

    int tid = threadIdx.x;
    if (tid < TILE) {
        int r = row0 + tid;
        s_idx[tid] = (r < cnt) ? sorted[e * T_TOKENS + r] : -1;
    }
    __syncthreads();   // also drains vmcnt -> DMA counting below starts at 0

    int wave = tid >> 6, lane = tid & 63;
    int wm = (wave >> 1) * 64, wn = (wave & 1) * 64;
    int lrow = lane & 15, lq = lane >> 4;
    // staging geometry: 16 rows / instruction (4 lanes x 16B per 64B row)
    int srow = lane >> 2, scol = lane & 3;
    int swz = scol ^ ((srow >> 1) & 3);    // global 16B-block index (XOR swizzle)

    // per-lane DMA source pointers (2 instrs each for A and B per stage);
    // pad rows (tok<0) read xb row 0 -- products land in discarded C rows
    const unsigned short* gA[2];
#pragma unroll
    for (int t = 0; t < 2; t++) {
        int tok = s_idx[wave * 32 + t * 16 + srow];
        gA[t] = xb + (size_t)(tok < 0 ? 0 : tok) * D + swz * 8;
    }
    const unsigned short* gB = Wb + (size_t)e * D * D
                             + (size_t)(bn * TILE + wave * 32 + srow) * D + swz * 8;

#define STAGE(K, KB) do {                                                       \
    _Pragma("unroll") for (int t = 0; t < 2; t++)                               \
        gl2lds16(gA[t] + (K) * BKD, &buf[KB][0][(wave * 32 + t * 16) * BKD]);   \
    _Pragma("unroll") for (int t = 0; t < 2; t++)                               \
        gl2lds16(gB + (size_t)(t * 16) * D + (K) * BKD,                         \
                 &buf[KB][1][(wave * 32 + t * 16) * BKD]);                      \
} while (0)

    f32x4 acc[4][4];
#pragma unroll
    for (int i = 0; i < 4; i++)
#pragma unroll
        for (int j2 = 0; j2 < 4; j2++)
            acc[i][j2] = (f32x4){0.f, 0.f, 0.f, 0.f};

    STAGE(0, 0);   // prologue: stage(0) in flight (4 DMAs)

#pragma unroll
    for (int step = 0; step < 16; step++) {
        // top barrier: prev step's ds_reads retired -> buf[(step+1)&1] is free
        asm volatile("s_waitcnt lgkmcnt(0)" ::: "memory");
        __builtin_amdgcn_s_barrier();
        __builtin_amdgcn_sched_barrier(0);
        if (step < 15) {
            STAGE(step + 1, (step + 1) & 1);   // issue next stage (4 DMAs)...
            __builtin_amdgcn_sched_barrier(0);
            // ...then wait ONLY for stage(step): 4 younger ops stay in flight
            asm volatile("s_waitcnt vmcnt(4)" ::: "memory");
        } else {
            asm volatile("s_waitcnt vmcnt(0)" ::: "memory");
        }
        __builtin_amdgcn_s_barrier();          // all waves' stage(step) visible
        __builtin_amdgcn_sched_barrier(0);
        const unsigned short* sA = buf[step & 1][0];
        const unsigned short* sB = buf[step & 1][1];
        int slot = lq ^ ((lrow >> 1) & 3);     // read-side swizzle slot
        __builtin_amdgcn_s_setprio(1);
        bf16x8 af[4], bfr[4];
#pragma unroll
        for (int i = 0; i < 4; i++)
            af[i] = *(const bf16x8*)&sA[(wm + 16 * i + lrow) * BKD + slot * 8];
#pragma unroll
        for (int j2 = 0; j2 < 4; j2++)
            bfr[j2] = *(const bf16x8*)&sB[(wn + 16 * j2 + lrow) * BKD + slot * 8];
#pragma unroll
        for (int i = 0; i < 4; i++)
#pragma unroll
            for (int j2 = 0; j2 < 4; j2++)
                acc[i][j2] = __builtin_amdgcn_mfma_f32_16x16x32_bf16(
                    af[i], bfr[j2], acc[i][j2], 0, 0, 0);
        __builtin_amdgcn_s_setprio(0);
    }
#undef STAGE

    // ---- coalesced epilogue: fold bias, stage C tile through LDS, write
    // full 512B row-segments (32 lanes x 16B) instead of scattered 64B chunks
#pragma unroll
    for (int j2 = 0; j2 < 4; j2++) {
        float bv = bias[e * D + bn * TILE + wn + 16 * j2 + lrow];
#pragma unroll
        for (int i = 0; i < 4; i++)
#pragma unroll
            for (int r = 0; r < 4; r++)
                acc[i][j2][r] += bv;
    }

    float* ct = (float*)&buf[0][0][0];   // 32 KB: 64 rows x 128 cols f32
#pragma unroll
    for (int p = 0; p < 2; p++) {
        // all MFMA ds_reads done (p=0) / pass-0 ct reads done (p=1)
        asm volatile("s_waitcnt lgkmcnt(0)" ::: "memory");
        __builtin_amdgcn_s_barrier();
        if ((wave >> 1) == p) {          // the 2 waves owning rows [64p,64p+64)
#pragma unroll
            for (int j2 = 0; j2 < 4; j2++)
#pragma unroll
                for (int i = 0; i < 4; i++)
#pragma unroll
                    for (int r = 0; r < 4; r++)
                        ct[(16 * i + lq * 4 + r) * TILE + wn + 16 * j2 + lrow]
                            = acc[i][j2][r];
        }
        asm volatile("s_waitcnt lgkmcnt(0)" ::: "memory");
        __builtin_amdgcn_s_barrier();
#pragma unroll
        for (int k = 0; k < 8; k++) {
            int u = tid + 256 * k;
            int row = u >> 5, ch = u & 31;
            int tok = s_idx[p * 64 + row];
            f32x4 v = *(const f32x4*)&ct[row * TILE + ch * 4];
            if (tok >= 0)
                *(f32x4*)&out[(size_t)tok * D + bn * TILE + ch * 4] = v;
        }
    }
}

// ---- fallback (tiny ws): fp32-load GEMM, fixed-region decode ----
__global__ __launch_bounds__(256) void moe_gemm_f32(
        const float* __restrict__ x, const float* __restrict__ W,
        const float* __restrict__ bias, const int* __restrict__ fill,
        const int* __restrict__ sorted, float* __restrict__ out) {
    __shared__ int s_idx[TILE];
    __shared__ unsigned short sA[TILE][BK + 8];
    __shared__ unsigned short sB[TILE][BK + 8];

    int bid = blockIdx.x;
    int e = bid & 7;
    int cnt = fill[e] + 1;
    int j = bid >> 3;
    int lt = j >> 2, bn = j & 3;
    int row0 = lt * TILE;
    if (row0 >= cnt) return;

    int tid = threadIdx.x;
    if (tid < TILE) {
        int r = row0 + tid;
        s_idx[tid] = (r < cnt) ? sorted[e * T_TOKENS + r] : -1;
    }
    __syncthreads();

    const float* Wbp = W + (size_t)e * D * D + (size_t)(bn * TILE) * D;

    f32x4 acc[4][4];
#pragma unroll
    for (int i = 0; i < 4; i++)
#pragma unroll
        for (int j2 = 0; j2 < 4; j2++)
            acc[i][j2] = (f32x4){0.f, 0.f, 0.f, 0.f};

    int wave = tid >> 6, lane = tid & 63;
    int wm = (wave >> 1) * 64, wn = (wave & 1) * 64;
    int lrow = lane & 15, lq = lane >> 4;

    for (int kk = 0; kk < D; kk += BK) {
#pragma unroll
        for (int i = 0; i < 8; i++) {
            int flat = tid + i * 256;
            int r = flat >> 4, c = (flat & 15) << 2;
            int tok = s_idx[r];
            float4 v = make_float4(0.f, 0.f, 0.f, 0.f);
            if (tok >= 0) v = *(const float4*)(x + (size_t)tok * D + kk + c);
            ushort4 w4;
            w4.x = f2bf(v.x); w4.y = f2bf(v.y); w4.z = f2bf(v.z); w4.w = f2bf(v.w);
            *(ushort4*)&sA[r][c] = w4;
        }
#pragma unroll
        for (int i = 0; i < 8; i++) {
            int flat = tid + i * 256;
            int r = flat >> 4, c = (flat & 15) << 2;
            float4 v = *(const float4*)(Wbp + (size_t)r * D + kk + c);
            ushort4 w4;
            w4.x = f2bf(v.x); w4.y = f2bf(v.y); w4.z = f2bf(v.z); w4.w = f2bf(v.w);
            *(ushort4*)&sB[r][c] = w4;
        }
        __syncthreads();
#pragma unroll
        for (int ks = 0; ks < 2; ks++) {
            bf16x8 af[4], bfr[4];
#pragma unroll
            for (int i = 0; i < 4; i++)
                af[i] = *(const bf16x8*)&sA[wm + 16 * i + lrow][ks * 32 + lq * 8];
#pragma unroll
            for (int j2 = 0; j2 < 4; j2++)
                bfr[j2] = *(const bf16x8*)&sB[wn + 16 * j2 + lrow][ks * 32 + lq * 8];
#pragma unroll
            for (int i = 0; i < 4; i++)
#pragma unroll
                for (int j2 = 0; j2 < 4; j2++)
                    acc[i][j2] = __builtin_amdgcn_mfma_f32_16x16x32_bf16(
                        af[i], bfr[j2], acc[i][j2], 0, 0, 0);
        }
        __syncthreads();
    }

#pragma unroll
    for (int j2 = 0; j2 < 4; j2++) {
        int ng = bn * TILE + wn + 16 * j2 + lrow;
        float bv = bias[e * D + ng];
#pragma unroll
        for (int i = 0; i < 4; i++) {
#pragma unroll
            for (int r = 0; r < 4; r++) {
                int mrow = wm + 16 * i + lq * 4 + r;
                int tok = s_idx[mrow];
                if (tok >= 0)
                    out[(size_t)tok * D + ng] = acc[i][j2][r] + bv;
            }
        }
    }
}

extern "C" void kernel_launch(void* const* d_in, const int* in_sizes, int n_in,
                              void* d_out, int out_size, void* d_ws, size_t ws_size,
                              hipStream_t stream) {
    const float* x    = (const float*)d_in[0];
    const int*   part = (const int*)d_in[1];
    const float* W    = (const float*)d_in[2];
    const float* b    = (const float*)d_in[3];
    float* out = (float*)d_out;

    const size_t xb_elems     = (size_t)T_TOKENS * D;             // bf16
    const size_t wb_elems     = (size_t)N_EXPERTS * D * D;        // bf16
    const size_t sorted_elems = (size_t)N_EXPERTS * T_TOKENS;     // int
    const size_t fast_bytes   = (xb_elems + wb_elems) * 2 + (sorted_elems + 8) * 4;
    const size_t slow_bytes   = (sorted_elems + 8) * 4;

    if (ws_size >= fast_bytes) {
        unsigned short* xb = (unsigned short*)d_ws;
        unsigned short* Wb = xb + xb_elems;
        int* sorted = (int*)(Wb + wb_elems);
        int* fill   = sorted + sorted_elems;

        hipMemsetAsync(fill, 0xFF, N_EXPERTS * sizeof(int), stream);   // fill = -1
        prep_kernel<<<SCATTER_BLOCKS + CONVW_BLOCKS + CONVX_BLOCKS, 256, 0, stream>>>(
            part, fill, sorted, W, Wb, x, xb);
        moe_gemm_dma<<<GEMM_GRID, 256, 0, stream>>>(xb, Wb, b, fill, sorted, out);
    } else if (ws_size >= slow_bytes) {
        int* sorted = (int*)d_ws;
        int* fill   = sorted + sorted_elems;

        hipMemsetAsync(fill, 0xFF, N_EXPERTS * sizeof(int), stream);
        prep_kernel<<<SCATTER_BLOCKS, 256, 0, stream>>>(
            part, fill, sorted, W, (unsigned short*)nullptr,
            x, (unsigned short*)nullptr);
        moe_gemm_f32<<<GEMM_GRID, 256, 0, stream>>>(x, W, b, fill, sorted, out);
    }
}